// Round 10
// baseline (209.454 us; speedup 1.0000x reference)
//
#include <hip/hip_runtime.h>
#include <hip/hip_bf16.h>

// Problem constants
#define TT   20
#define TS   19          // T-1 steps
#define BB   16
#define HH   128
#define WW   128
#define CHN  64
#define NOUT 10
#define BETA 0.9f
#define THRV 1.0f

#define SPIKESUM_ELEMS (TS*BB*CHN)           // 19,456 ints
#define SPIKESUM_BYTES (SPIKESUM_ELEMS*4)    // 77,824 B

#define RSTRIDE  24      // dwords per staged row (18 used + 6 pad; offsets 0/24/16/8 mod 32 -> <=2-way)
#define PLSTRIDE 96      // dwords per plane (4 rows)
#define WVSTRIDE 192     // dwords per wave region (2 planes)

typedef __attribute__((ext_vector_type(8))) short short8;
typedef __attribute__((ext_vector_type(4))) float float4v;
typedef __attribute__((ext_vector_type(4))) int   int4v;

// round-to-nearest-even fp32 -> bf16 bits
__device__ __forceinline__ unsigned rne16(float f) {
    unsigned u = __float_as_uint(f);
    return (u + 0x7fffu + ((u >> 16) & 1u)) >> 16;
}
__device__ __forceinline__ float b2f(unsigned us) {
    return __uint_as_float(us << 16);
}

// ---------------------------------------------------------------------------
// Fused flow-diff + 3x3 conv (bf16-split MFMA) + LIF scan + spike count.
//
// BARRIER-FREE: each wave stages its own 4-row x 18-px flow window into a
// wave-private LDS region (72 slots, ~1.1 per lane). LDS ops from one wave
// execute in order on the DS pipe, so write->read needs no __syncthreads —
// only compiler fences (asm memory clobbers, zero instructions). This
// removes the per-t vmcnt(0)/lgkmcnt(0) barrier drains (which waited on
// the contended spikesum atomic acks) and decouples the 4 waves.
//
// Wave = 16 px x 2 output rows x all 64 ch. x register-carried (rb=ra
// rotation, one float2 load/slot/t, issued BEFORE the atomic so the atomic
// ack is never awaited). Counts byte-packed: cpk accumulates cg counts in
// 4 bytes (max 32 < 256), 2 shfl_xor reduce over quads, bfe extract.
//
// C-init fresh zero per t (R8: in-place C chains kill MFMA/VALU overlap).
// k-remap: quad = ky, j = kx*2+ci (j<6); k=24 tap: A = 1.0, B = bias.
// u = Ah*Bh + Al*Bh + Ah*Bl (drops Alo*Blo ~ 2^-16 relative).
// A layout: m(pixel) = lane&15, k = quad*8+j. C/D: row(pixel) = q*4+reg,
// col(channel-in-group) = lane&15.
// ---------------------------------------------------------------------------
__global__ __launch_bounds__(256, 4) void lif_main(const float* __restrict__ x,
                                                   const float* __restrict__ w_conv,
                                                   const float* __restrict__ b_conv,
                                                   int* __restrict__ spikesum) {
    __shared__ unsigned lds[4 * WVSTRIDE];       // 3072 B, single-buffered

    const float2* xp2 = (const float2*)x;        // pixel-granular (ci pair)

    const int tid  = threadIdx.x;
    const int lane = tid & 63;
    const int wv   = __builtin_amdgcn_readfirstlane(tid >> 6); // uniform 0..3
    const int bx   = blockIdx.x;                 // 0..1 : pixel half
    const int r0   = blockIdx.y << 1;            // first of 2 output rows
    const int bz   = blockIdx.z;                 // batch
    const int q    = lane >> 4;                  // quad
    const int col  = lane & 15;
    const int x0w  = (bx << 6) + (wv << 4);      // wave's 16-px base

    // ---- t-invariant wave-private staging slots (slot = one pixel pair)
    // slot s (0..71): r = s/18, i = s%18 ; y = r0-1+r ; px = x0w-1+i
    const int  s0r = lane / 18, s0i = lane - s0r * 18;
    const int  y0s = r0 - 1 + s0r;
    const int  p0s = x0w - 1 + s0i;
    const bool v0  = ((unsigned)y0s < (unsigned)HH) && ((unsigned)p0s < (unsigned)WW);
    const int  g0  = v0 ? (y0s * WW + p0s) : 0;
    const int  a0  = wv * WVSTRIDE + s0r * RSTRIDE + s0i;

    const bool act1 = (lane < 8);                // slots 64..71 = (r=3, i=10..17)
    const int  y1s = r0 + 2;
    const int  p1s = x0w + 9 + lane;
    const bool v1  = act1 && ((unsigned)y1s < (unsigned)HH) && ((unsigned)p1s < (unsigned)WW);
    const int  g1  = v1 ? (y1s * WW + p1s) : 0;
    const int  a1  = wv * WVSTRIDE + 3 * RSTRIDE + 10 + lane;

    // ---- B fragments: k = q*8+j ; q<3,j<6: weights ; q==3,j==0 (k=24): bias
    short8 Bh[4], Bl[4];
#pragma unroll
    for (int cg = 0; cg < 4; ++cg) {
        int hi_i[4] = {0, 0, 0, 0}, lo_i[4] = {0, 0, 0, 0};
        if (q < 3) {
#pragma unroll
            for (int j = 0; j < 6; ++j) {
                float w = w_conv[((q * 3 + (j >> 1)) * 2 + (j & 1)) * CHN + cg * 16 + col];
                unsigned hs = rne16(w);
                unsigned ls = rne16(w - b2f(hs));
                hi_i[j >> 1] |= (int)(hs << (16 * (j & 1)));
                lo_i[j >> 1] |= (int)(ls << (16 * (j & 1)));
            }
        } else {
            float bb = b_conv[cg * 16 + col];
            unsigned hs = rne16(bb);
            unsigned ls = rne16(bb - b2f(hs));
            hi_i[0] = (int)hs;                   // k=24, low half
            lo_i[0] = (int)ls;
        }
        int4v hv = {hi_i[0], hi_i[1], hi_i[2], hi_i[3]};
        int4v lv = {lo_i[0], lo_i[1], lo_i[2], lo_i[3]};
        Bh[cg] = __builtin_bit_cast(short8, hv);
        Bl[cg] = __builtin_bit_cast(short8, lv);
    }

    float V0[4][4], V1[4][4];                    // membrane, rows r0, r0+1
#pragma unroll
    for (int cg = 0; cg < 4; ++cg)
#pragma unroll
        for (int r = 0; r < 4; ++r) { V0[cg][r] = 0.f; V1[cg][r] = 0.f; }

    // ---- preheader: rb = x[0], ra = x[1] (invalid slots stay 0 forever)
    float2 rb0 = {0.f, 0.f}, ra0 = {0.f, 0.f};
    float2 rb1 = {0.f, 0.f}, ra1 = {0.f, 0.f};
    {
        const int sA = bz * (HH * WW);
        const int sB = (BB + bz) * (HH * WW);
        if (v0) { rb0 = xp2[sA + g0]; ra0 = xp2[sB + g0]; }
        if (v1) { rb1 = xp2[sA + g1]; ra1 = xp2[sB + g1]; }
    }

    for (int t = 0; t < TS; ++t) {
        // ---- pack flow = ra - rb into wave-private hi/lo planes
        {
            float d0 = ra0.x - rb0.x, d1 = ra0.y - rb0.y;
            unsigned ph0 = rne16(d0), ph1 = rne16(d1);
            unsigned pl0 = rne16(d0 - b2f(ph0)), pl1 = rne16(d1 - b2f(ph1));
            lds[a0]            = ph0 | (ph1 << 16);
            lds[a0 + PLSTRIDE] = pl0 | (pl1 << 16);
        }
        if (act1) {
            float d0 = ra1.x - rb1.x, d1 = ra1.y - rb1.y;
            unsigned ph0 = rne16(d0), ph1 = rne16(d1);
            unsigned pl0 = rne16(d0 - b2f(ph0)), pl1 = rne16(d1 - b2f(ph1));
            lds[a1]            = ph0 | (ph1 << 16);
            lds[a1 + PLSTRIDE] = pl0 | (pl1 << 16);
        }
        __asm volatile("" ::: "memory");         // keep reads below writes

        // ---- rotate + issue loads for next t (slice t+2); these are OLDER
        // than this t's atomic, so waiting on them never waits on atomics.
        if (t < TS - 1) {
            rb0 = ra0; rb1 = ra1;
            const int sC = ((t + 2) * BB + bz) * (HH * WW);
            if (v0) ra0 = xp2[sC + g0];
            if (v1) ra1 = xp2[sC + g1];
        }

        // ---- A fragments: rowset0 = staged rows q, rowset1 = rows q+1
        unsigned h0, h1, h2, l0, l1, l2, h3, h4, h5, l3, l4, l5;
        if (q < 3) {
            const unsigned* hp = lds + wv * WVSTRIDE + q * RSTRIDE + col;
            const unsigned* lp = hp + PLSTRIDE;
            h0 = hp[0]; h1 = hp[1]; h2 = hp[2];
            h3 = hp[RSTRIDE]; h4 = hp[RSTRIDE + 1]; h5 = hp[RSTRIDE + 2];
            l0 = lp[0]; l1 = lp[1]; l2 = lp[2];
            l3 = lp[RSTRIDE]; l4 = lp[RSTRIDE + 1]; l5 = lp[RSTRIDE + 2];
        } else {
            h0 = 0x3f80u; l0 = 0; h3 = 0x3f80u; l3 = 0;   // k=24 tap = 1.0
            h1 = h2 = l1 = l2 = 0;
            h4 = h5 = l4 = l5 = 0;
        }
        __asm volatile("" ::: "memory");         // keep next writes below reads

        int4v a0h = {(int)h0, (int)h1, (int)h2, 0};
        int4v a0l = {(int)l0, (int)l1, (int)l2, 0};
        int4v a1h = {(int)h3, (int)h4, (int)h5, 0};
        int4v a1l = {(int)l3, (int)l4, (int)l5, 0};
        short8 A0h = __builtin_bit_cast(short8, a0h);
        short8 A0l = __builtin_bit_cast(short8, a0l);
        short8 A1h = __builtin_bit_cast(short8, a1h);
        short8 A1l = __builtin_bit_cast(short8, a1l);

        // ---- conv (MFMA) + LIF + byte-packed counts
        unsigned cpk = 0;
#pragma unroll
        for (int cg = 0; cg < 4; ++cg) {
            float4v u0 = {0.f, 0.f, 0.f, 0.f};
            float4v u1 = {0.f, 0.f, 0.f, 0.f};
            u0 = __builtin_amdgcn_mfma_f32_16x16x32_bf16(A0h, Bh[cg], u0, 0, 0, 0);
            u1 = __builtin_amdgcn_mfma_f32_16x16x32_bf16(A1h, Bh[cg], u1, 0, 0, 0);
            u0 = __builtin_amdgcn_mfma_f32_16x16x32_bf16(A0l, Bh[cg], u0, 0, 0, 0);
            u1 = __builtin_amdgcn_mfma_f32_16x16x32_bf16(A1l, Bh[cg], u1, 0, 0, 0);
            u0 = __builtin_amdgcn_mfma_f32_16x16x32_bf16(A0h, Bl[cg], u0, 0, 0, 0);
            u1 = __builtin_amdgcn_mfma_f32_16x16x32_bf16(A1h, Bl[cg], u1, 0, 0, 0);
            const unsigned inc = 1u << (8 * cg);
#pragma unroll
            for (int r = 0; r < 4; ++r) {
                float vv0 = fmaf(BETA, V0[cg][r], u0[r]);
                bool  sp0 = vv0 > THRV;
                cpk += sp0 ? inc : 0u;
                V0[cg][r] = sp0 ? (vv0 - THRV) : vv0;
                float vv1 = fmaf(BETA, V1[cg][r], u1[r]);
                bool  sp1 = vv1 > THRV;
                cpk += sp1 ? inc : 0u;
                V1[cg][r] = sp1 ? (vv1 - THRV) : vv1;
            }
        }
        cpk += __shfl_xor(cpk, 16);              // reduce over quads
        cpk += __shfl_xor(cpk, 32);
        int my = (int)((cpk >> (8 * q)) & 0xffu); // byte q = cg q ; ch = q*16+col = lane
        atomicAdd(&spikesum[(t * BB + bz) * CHN + lane], my);
    }
}

// ---------------------------------------------------------------------------
// head: one block per batch b. Computes logits[t][b][:], readout[b][:]
// (mean over t), and (block 0 only) sr. Writes every out element -> no
// memset(out), no atomics.
// ---------------------------------------------------------------------------
__global__ __launch_bounds__(256) void head_kernel(const int* __restrict__ spikesum,
                                                   const float* __restrict__ w_head,
                                                   const float* __restrict__ b_head,
                                                   float* __restrict__ out) {
    __shared__ float lg_s[TS][NOUT];
    const int b = blockIdx.x, tid = threadIdx.x;

    if (tid < TS * NOUT) {
        const int t = tid / NOUT, o = tid - t * NOUT;
        const int* cnt = spikesum + (t * BB + b) * CHN;
        float acc = 0.f;
#pragma unroll
        for (int ch = 0; ch < CHN; ++ch)
            acc = fmaf((float)cnt[ch], w_head[ch * NOUT + o], acc);
        float lg = acc * (1.f / (HH * WW)) + b_head[o];
        out[BB * NOUT + (t * BB + b) * NOUT + o] = lg;
        lg_s[t][o] = lg;
    }
    __syncthreads();
    if (tid < NOUT) {
        float a = 0.f;
#pragma unroll
        for (int t = 0; t < TS; ++t) a += lg_s[t][tid];
        out[b * NOUT + tid] = a * (1.f / TS);
    }
    if (b == 0) {
        int s = 0;
        for (int i = tid; i < SPIKESUM_ELEMS; i += 256) s += spikesum[i];
#pragma unroll
        for (int off = 32; off > 0; off >>= 1) s += __shfl_down(s, off);
        __shared__ int red[4];
        if ((tid & 63) == 0) red[tid >> 6] = s;
        __syncthreads();
        if (tid == 0)
            out[BB * NOUT + TS * BB * NOUT] =
                (float)(red[0] + red[1] + red[2] + red[3]) *
                (1.f / ((float)TS * BB * HH * WW * CHN));
    }
}

// ---------------------------------------------------------------------------
extern "C" void kernel_launch(void* const* d_in, const int* in_sizes, int n_in,
                              void* d_out, int out_size, void* d_ws, size_t ws_size,
                              hipStream_t stream) {
    (void)in_sizes; (void)n_in; (void)out_size; (void)ws_size;
    const float* x      = (const float*)d_in[0];
    const float* w_conv = (const float*)d_in[1];
    const float* b_conv = (const float*)d_in[2];
    const float* w_head = (const float*)d_in[3];
    const float* b_head = (const float*)d_in[4];
    float* out      = (float*)d_out;
    int*   spikesum = (int*)d_ws;

    (void)hipMemsetAsync(d_ws, 0, SPIKESUM_BYTES, stream);

    lif_main<<<dim3(2, HH / 2, BB), 256, 0, stream>>>(x, w_conv, b_conv, spikesum);
    head_kernel<<<BB, 256, 0, stream>>>(spikesum, w_head, b_head, out);
}